// Round 5
// baseline (185.371 us; speedup 1.0000x reference)
//
#include <hip/hip_runtime.h>
#include <hip/hip_bf16.h>

// Problem constants: D=1024, H=16, HD=64, B=2, N=1024, rows = B*N = 2048.

typedef __attribute__((ext_vector_type(8))) short bf16x8;
typedef __attribute__((ext_vector_type(4))) float f32x4;

// ws layout (float offsets).
#define OFF_HBF  0                 // h cast to bf16        [2048][1024] us
#define OFF_XBF  1048576           // X (gelu out) bf16     [2048][1024] us
#define OFF_WVBF 2097152           // Wv bf16               [1024][1024] us
#define OFF_MBF  2621440           // M = Wo(x)fu_W2 bf16   [1024][1024] us
#define OFF_W1A  3145728           // fu_W1[:,:,0:64] bf16  [16][64][64] us
#define OFF_HBAR 3178496           // mean of h over n [2][1024]
#define OFF_BIAS 3180544           // bias_vec = Wo @ fu_b2 [1024]

__device__ __forceinline__ unsigned short f2bf(float f) {
    unsigned int u = __float_as_uint(f);
    u += 0x7fffu + ((u >> 16) & 1u);   // round-to-nearest-even
    return (unsigned short)(u >> 16);
}

__device__ __forceinline__ void async_load16(const void* g, void* l) {
    __builtin_amdgcn_global_load_lds(
        (const __attribute__((address_space(1))) unsigned int*)g,
        (__attribute__((address_space(3))) unsigned int*)l, 16, 0, 0);
}

// ---------------------------------------------------------------------------
// P1 (grid 752): all mutually-independent prep work, no atomics, no memset.
//   [0,128)   : cast h->bf16 (16 rows/blk, float4)
//   [128,160) : hbar[b,d] = mean_n h[b,n,d]  (direct reduction, 64 cols/blk)
//   [160,416) : M[e',h64+e] = sum_f Wo[e',h64+f]*fu_W2[h,f,e] (LDS-staged)
//   [416,432) : bias[e'] = Wo[e',:].fu_b2 (coalesced rows + wave shfl reduce)
//   [432,496) : cast fu_W1[:,:,0:64] -> W1a bf16
//   [496,752) : cast Wv->bf16 (4096 elems/blk)
// ---------------------------------------------------------------------------
__global__ __launch_bounds__(256) void k_prep(const float* __restrict__ h,
                                              const float* __restrict__ Wv,
                                              const float* __restrict__ fu_W1,
                                              const float* __restrict__ Wo,
                                              const float* __restrict__ fu_W2,
                                              const float* __restrict__ fu_b2,
                                              unsigned short* __restrict__ hbf,
                                              unsigned short* __restrict__ Wvbf,
                                              unsigned short* __restrict__ W1abf,
                                              unsigned short* __restrict__ Mbf,
                                              float* __restrict__ hbar,
                                              float* __restrict__ bias) {
    __shared__ float smem[8384];
    int blk = blockIdx.x, tid = threadIdx.x;
    if (blk < 128) {
        // ---- h cast ----
        int b = blk >> 6, chunk = blk & 63;
        int n0 = chunk * 16, d0 = tid * 4;
        const float* hb = h + (size_t)b * 1048576 + d0;
        unsigned short* ob = hbf + (size_t)b * 1048576 + d0;
#pragma unroll
        for (int i = 0; i < 16; ++i) {
            float4 v = *(const float4*)(hb + (size_t)(n0 + i) * 1024);
            *(ushort4*)(ob + (size_t)(n0 + i) * 1024) =
                make_ushort4(f2bf(v.x), f2bf(v.y), f2bf(v.z), f2bf(v.w));
        }
    } else if (blk < 160) {
        // ---- hbar direct reduction: 32 blocks, 64 cols each ----
        f32x4* psum = (f32x4*)smem;            // [256]
        int blk2 = blk - 128;
        int b = blk2 >> 4, chunk = blk2 & 15;
        int c0 = chunk * 64 + (tid & 15) * 4;
        int ns = tid >> 4;                     // 16 slices of 64 n
        const float* hb = h + (size_t)b * 1048576 + c0;
        float4 s = make_float4(0.f, 0.f, 0.f, 0.f);
        for (int i = 0; i < 64; ++i) {
            float4 v = *(const float4*)(hb + (size_t)(ns * 64 + i) * 1024);
            s.x += v.x; s.y += v.y; s.z += v.z; s.w += v.w;
        }
        psum[(tid & 15) * 16 + ns] = (f32x4){s.x, s.y, s.z, s.w};
        __syncthreads();
        if (tid < 16) {
            f32x4 a = (f32x4){0.f, 0.f, 0.f, 0.f};
#pragma unroll
            for (int j = 0; j < 16; ++j) a += psum[tid * 16 + j];
            a *= (1.0f / 1024.0f);
            *(float4*)(hbar + b * 1024 + chunk * 64 + tid * 4) =
                make_float4(a[0], a[1], a[2], a[3]);
        }
    } else if (blk < 416) {
        // ---- M collapse ----
        float* W2s = smem;               // [f][e] stride 65
        float* Wos = smem + 4160;        // [r][f] stride 65
        int blk2 = blk - 160;
        int rc = blk2 >> 4, hh = blk2 & 15;
        int r0 = rc * 64;
#pragma unroll
        for (int i = 0; i < 16; ++i) {
            int idx = tid + i * 256;
            int f = idx >> 6, e = idx & 63;
            W2s[f * 65 + e] = fu_W2[hh * 4096 + idx];
            Wos[f * 65 + e] = Wo[(size_t)(r0 + f) * 1024 + hh * 64 + e];
        }
        __syncthreads();
        int ty = tid >> 3, tx = tid & 7;
        int r1 = 2 * ty, r2 = 2 * ty + 1, e0 = tx * 8;
        float acc0[8], acc1[8];
#pragma unroll
        for (int j = 0; j < 8; ++j) { acc0[j] = 0.f; acc1[j] = 0.f; }
        for (int f = 0; f < 64; ++f) {
            float a0 = Wos[r1 * 65 + f], a1 = Wos[r2 * 65 + f];
            const float* w2r = &W2s[f * 65 + e0];
#pragma unroll
            for (int j = 0; j < 8; ++j) {
                float b = w2r[j];
                acc0[j] += a0 * b;
                acc1[j] += a1 * b;
            }
        }
        unsigned short* m1 = Mbf + (size_t)(r0 + r1) * 1024 + hh * 64 + e0;
        unsigned short* m2 = Mbf + (size_t)(r0 + r2) * 1024 + hh * 64 + e0;
        *(ushort4*)(m1) = make_ushort4(f2bf(acc0[0]), f2bf(acc0[1]), f2bf(acc0[2]), f2bf(acc0[3]));
        *(ushort4*)(m1 + 4) = make_ushort4(f2bf(acc0[4]), f2bf(acc0[5]), f2bf(acc0[6]), f2bf(acc0[7]));
        *(ushort4*)(m2) = make_ushort4(f2bf(acc1[0]), f2bf(acc1[1]), f2bf(acc1[2]), f2bf(acc1[3]));
        *(ushort4*)(m2 + 4) = make_ushort4(f2bf(acc1[4]), f2bf(acc1[5]), f2bf(acc1[6]), f2bf(acc1[7]));
    } else if (blk < 432) {
        // ---- bias: 16 blocks x 64 rows, coalesced + wave shfl reduce ----
        float* b2s = smem;               // [1024]
        *(float4*)(b2s + tid * 4) = *(const float4*)(fu_b2 + tid * 4);
        __syncthreads();
        int r0 = (blk - 416) * 64;
        int w = tid >> 6, lane = tid & 63;
        int c0 = lane * 16;
#pragma unroll
        for (int g = 0; g < 16; ++g) {
            int r = r0 + g * 4 + w;
            const float* wo = Wo + (size_t)r * 1024 + c0;
            float p = 0.f;
#pragma unroll
            for (int j = 0; j < 4; ++j) {
                float4 a = *(const float4*)(wo + j * 4);
                float4 b = *(const float4*)(b2s + c0 + j * 4);
                p += a.x * b.x + a.y * b.y + a.z * b.z + a.w * b.w;
            }
#pragma unroll
            for (int off = 32; off > 0; off >>= 1) p += __shfl_down(p, off, 64);
            if (lane == 0) bias[r] = p;
        }
    } else if (blk < 496) {
        // ---- W1a cast ----
        int blk2 = blk - 432;                 // 0..63
        int hh = blk2 >> 2, q = blk2 & 3;
        int e = q * 16 + (tid >> 4);
        int k4 = (tid & 15) * 4;
        float4 v = *(const float4*)(fu_W1 + (size_t)(hh * 64 + e) * 192 + k4);
        *(ushort4*)(W1abf + hh * 4096 + e * 64 + k4) =
            make_ushort4(f2bf(v.x), f2bf(v.y), f2bf(v.z), f2bf(v.w));
    } else {
        // ---- Wv cast: 256 blocks x 4096 ----
        int base = (blk - 496) * 4096;
#pragma unroll
        for (int j = 0; j < 4; ++j) {
            int i0 = base + j * 1024 + tid * 4;
            float4 v = *(const float4*)(Wv + i0);
            *(ushort4*)(Wvbf + i0) =
                make_ushort4(f2bf(v.x), f2bf(v.y), f2bf(v.z), f2bf(v.w));
        }
    }
}

// ---------------------------------------------------------------------------
// GEMM: C = A[2048x1024] @ W[1024x1024]^T, bf16 MFMA.
// BM=BN=64, BK=64, 256 thr (4 waves, each 32x32 = 2x2 16x16 tiles);
// grid (32,16) = 512 blocks = 2 blocks/CU.
// LDS XOR-swizzle: byte(r,c) = r*128 + (((c>>3)^(r&7))<<4) + (c&7)*2.
// MODE 1: epilogue = in-block cvec (mf = Wvbf.hbar, cadd = fu_b1+(W1b+W1c)mf;
//         16x-redundant across row-blocks but fully parallel, kills the old
//         32-block k_cvec node) + per-head 64x64 MLP (HF->LDS A-layout, W1a
//         as B via MFMA) + exact GELU -> X bf16 (coalesced via LDS).
// MODE 0: + bias -> fp32 out via LDS float4 stores; fused tail in block (0,0).
// ---------------------------------------------------------------------------
template <int MODE>
__global__ __launch_bounds__(256) void k_mm(const unsigned short* __restrict__ A,
                                            const unsigned short* __restrict__ Bw,
                                            void* __restrict__ CoutV,
                                            const unsigned short* __restrict__ W1a,
                                            const float* __restrict__ hbar,
                                            const float* __restrict__ fu_W1,
                                            const float* __restrict__ fu_b1,
                                            const float* __restrict__ bias,
                                            const int* __restrict__ prev_idx,
                                            const float* __restrict__ chain_ratio) {
    __shared__ __align__(16) char smem[18432];
    char* As = smem;            // 8 KB
    char* Bs = smem + 8192;     // 8 KB
    const int tid = threadIdx.x;
    const int w = tid >> 6, lane = tid & 63;
    const int rowBase = blockIdx.x * 64, colBase = blockIdx.y * 64;
    const int wmh = (w >> 1) * 32, wnh = (w & 1) * 32;
    const int lr = lane >> 3;                 // staging row within 8-row chunk
    const int ssrc = ((lane & 7) ^ lr) * 8;   // swizzled source k offset (elems)
    const int m_lane = lane & 15, quad = lane >> 4;

    if (MODE == 0 && blockIdx.x == 0 && blockIdx.y == 0) {
        // fused tail: targets + strength (closed-form: uniform softmax over a
        // broadcast scalar logit -> target 511 / chained prev_idx).
        float* out = (float*)CoutV;
        float cr = chain_ratio[0];
        float thr = floorf(1024.0f / (1.0f + expf(-cr)));
        float strength = 1.0f - logf(1.0f / 1024.0f + 1e-8f);
        for (int i = tid; i < 2048; i += 256) {
            int n = i & 1023;
            float fwd = 511.0f;
            if ((float)n >= thr) {
                int p = prev_idx[i];
                p = p < 0 ? 0 : (p > 1023 ? 1023 : p);
                fwd = (float)p;
            }
            out[2097152 + i] = fwd;
            out[2097152 + 2048 + i] = 511.0f;
            out[2097152 + 4096 + i] = strength;
        }
    }

    const unsigned short* Ag0 = A + (size_t)(rowBase + w * 8 + lr) * 1024 + ssrc;
    const unsigned short* Ag1 = Ag0 + (size_t)32 * 1024;
    const unsigned short* Bg0 = Bw + (size_t)(colBase + w * 8 + lr) * 1024 + ssrc;
    const unsigned short* Bg1 = Bg0 + (size_t)32 * 1024;
    char* AsW = As + w * 1024;   // wave-uniform LDS staging bases
    char* BsW = Bs + w * 1024;

    f32x4 acc[2][2];
#pragma unroll
    for (int i = 0; i < 2; ++i)
#pragma unroll
        for (int j = 0; j < 2; ++j) acc[i][j] = (f32x4){0.f, 0.f, 0.f, 0.f};

    for (int k0 = 0; k0 < 1024; k0 += 64) {
        __syncthreads();                       // prev iter's frag reads done
        async_load16(Ag0 + k0, AsW);
        async_load16(Ag1 + k0, AsW + 4096);
        async_load16(Bg0 + k0, BsW);
        async_load16(Bg1 + k0, BsW + 4096);
        __syncthreads();                       // vmcnt(0) drain before barrier
#pragma unroll
        for (int kh = 0; kh < 2; ++kh) {
            const int seg = kh * 4 + quad;
            bf16x8 af[2], bfr[2];
#pragma unroll
            for (int mt = 0; mt < 2; ++mt) {
                int m = wmh + mt * 16 + m_lane;
                af[mt] = *(const bf16x8*)(As + m * 128 + ((seg ^ (m & 7)) << 4));
            }
#pragma unroll
            for (int nt = 0; nt < 2; ++nt) {
                int n = wnh + nt * 16 + m_lane;
                bfr[nt] = *(const bf16x8*)(Bs + n * 128 + ((seg ^ (n & 7)) << 4));
            }
#pragma unroll
            for (int mt = 0; mt < 2; ++mt)
#pragma unroll
                for (int nt = 0; nt < 2; ++nt)
                    acc[mt][nt] = __builtin_amdgcn_mfma_f32_16x16x32_bf16(
                        af[mt], bfr[nt], acc[mt][nt], 0, 0, 0);
        }
    }

    if (MODE == 0) {
        float* out = (float*)CoutV;
        float* Os = (float*)smem;              // [64][68] fp32 = 17408 B
        __syncthreads();                       // main-loop LDS reads done
#pragma unroll
        for (int nt = 0; nt < 2; ++nt) {
            int c = wnh + nt * 16 + m_lane;
            float bj = bias[colBase + c];
#pragma unroll
            for (int mt = 0; mt < 2; ++mt)
#pragma unroll
                for (int r4 = 0; r4 < 4; ++r4) {
                    int r = wmh + mt * 16 + quad * 4 + r4;
                    Os[r * 68 + c] = acc[mt][nt][r4] + bj;
                }
        }
        __syncthreads();
#pragma unroll
        for (int j = 0; j < 4; ++j) {
            int sidx = tid + j * 256;
            int r = sidx >> 4, sc = sidx & 15;
            float4 v = *(const float4*)&Os[r * 68 + sc * 4];
            *(float4*)&out[(size_t)(rowBase + r) * 1024 + colBase + sc * 4] = v;
        }
    } else {
        unsigned short* Xbf = (unsigned short*)CoutV;
        const int hh = blockIdx.y;             // head for this 64-col block
        const int b = rowBase >> 10;
        float* psum = (float*)(smem + 16384);  // [256]
        float* mfs  = (float*)(smem + 17408);  // [64]
        float* cadd = (float*)(smem + 17664);  // [64]
        __syncthreads();                       // main-loop LDS reads done
        // stage W1a head block [64 e_out][64 e_in] into Bs (swizzled, async)
        const unsigned short* Wg = W1a + hh * 4096 + (w * 8 + lr) * 64 + ssrc;
        async_load16(Wg, BsW);
        async_load16(Wg + 32 * 64, BsW + 4096);
        // cvec partials: thread (e=tid>>2, sl=tid&3) sums 256 d of Wvbf.hbar
        {
            int e = tid >> 2, sl = tid & 3;
            const unsigned int* wv =
                (const unsigned int*)(Bw + (size_t)(hh * 64 + e) * 1024 + sl * 256);
            const float* hb = hbar + b * 1024 + sl * 256;
            float s = 0.f;
            for (int i = 0; i < 32; ++i) {
                uint4 u = *(const uint4*)(wv + i * 4);        // 8 bf16
                float4 h0 = *(const float4*)(hb + i * 8);
                float4 h1 = *(const float4*)(hb + i * 8 + 4);
                s += __uint_as_float(u.x << 16) * h0.x
                   + __uint_as_float(u.x & 0xffff0000u) * h0.y
                   + __uint_as_float(u.y << 16) * h0.z
                   + __uint_as_float(u.y & 0xffff0000u) * h0.w
                   + __uint_as_float(u.z << 16) * h1.x
                   + __uint_as_float(u.z & 0xffff0000u) * h1.y
                   + __uint_as_float(u.w << 16) * h1.z
                   + __uint_as_float(u.w & 0xffff0000u) * h1.w;
            }
            psum[tid] = s;                     // tid == e*4+sl
        }
        // write HF (bf16 of acc) into As in A-fragment (swizzled) layout
#pragma unroll
        for (int mt = 0; mt < 2; ++mt)
#pragma unroll
            for (int nt = 0; nt < 2; ++nt) {
                int c = wnh + nt * 16 + m_lane;
#pragma unroll
                for (int r4 = 0; r4 < 4; ++r4) {
                    int r = wmh + mt * 16 + quad * 4 + r4;
                    *(unsigned short*)(As + r * 128 + (((c >> 3) ^ (r & 7)) << 4) +
                                       (c & 7) * 2) = f2bf(acc[mt][nt][r4]);
                }
            }
        __syncthreads();                       // drains vmcnt -> W1a staged; psum visible
        if (tid < 64)
            mfs[tid] = psum[tid * 4] + psum[tid * 4 + 1] +
                       psum[tid * 4 + 2] + psum[tid * 4 + 3];
        f32x4 acc2[2][2];
#pragma unroll
        for (int i = 0; i < 2; ++i)
#pragma unroll
            for (int j = 0; j < 2; ++j) acc2[i][j] = (f32x4){0.f, 0.f, 0.f, 0.f};
#pragma unroll
        for (int kh = 0; kh < 2; ++kh) {
            const int seg = kh * 4 + quad;
            bf16x8 af[2], bfr[2];
#pragma unroll
            for (int mt = 0; mt < 2; ++mt) {
                int m = wmh + mt * 16 + m_lane;
                af[mt] = *(const bf16x8*)(As + m * 128 + ((seg ^ (m & 7)) << 4));
            }
#pragma unroll
            for (int nt = 0; nt < 2; ++nt) {
                int n = wnh + nt * 16 + m_lane;
                bfr[nt] = *(const bf16x8*)(Bs + n * 128 + ((seg ^ (n & 7)) << 4));
            }
#pragma unroll
            for (int mt = 0; mt < 2; ++mt)
#pragma unroll
                for (int nt = 0; nt < 2; ++nt)
                    acc2[mt][nt] = __builtin_amdgcn_mfma_f32_16x16x32_bf16(
                        af[mt], bfr[nt], acc2[mt][nt], 0, 0, 0);
        }
        __syncthreads();                       // HF reads done; mfs visible
        if (tid < 64) {
            const float* w1 = fu_W1 + (size_t)(hh * 64 + tid) * 192;
            float a = fu_b1[hh * 64 + tid];
#pragma unroll 4
            for (int k = 0; k < 64; k += 4) {
                float4 wa = *(const float4*)(w1 + 64 + k);
                float4 wb = *(const float4*)(w1 + 128 + k);
                float4 m4 = *(const float4*)(mfs + k);
                a += (wa.x + wb.x) * m4.x + (wa.y + wb.y) * m4.y +
                     (wa.z + wb.z) * m4.z + (wa.w + wb.w) * m4.w;
            }
            cadd[tid] = a;
        }
        __syncthreads();                       // cadd visible; As reusable
#pragma unroll
        for (int mt = 0; mt < 2; ++mt)
#pragma unroll
            for (int nt = 0; nt < 2; ++nt) {
                int c = wnh + nt * 16 + m_lane;
                float ca = cadd[c];
#pragma unroll
                for (int r4 = 0; r4 < 4; ++r4) {
                    int r = wmh + mt * 16 + quad * 4 + r4;
                    float t = acc2[mt][nt][r4] + ca;
                    t = 0.5f * t * (1.0f + erff(t * 0.70710678118654752f));
                    *(unsigned short*)(As + r * 128 + c * 2) = f2bf(t);  // plain
                }
            }
        __syncthreads();
        // coalesced X store: 64 rows x 8 16B-segs = 512, 2 per thread
#pragma unroll
        for (int j = 0; j < 2; ++j) {
            int seg = tid + j * 256;
            int r = seg >> 3, s = seg & 7;
            float4 v = *(const float4*)(As + r * 128 + s * 16);
            *(float4*)((char*)Xbf +
                       ((size_t)(rowBase + r) * 1024 + colBase + s * 8) * 2) = v;
        }
    }
}

// ---------------------------------------------------------------------------
extern "C" void kernel_launch(void* const* d_in, const int* in_sizes, int n_in,
                              void* d_out, int out_size, void* d_ws, size_t ws_size,
                              hipStream_t stream) {
    const float* h      = (const float*)d_in[0];
    const int*   prev   = (const int*)d_in[1];
    // d_in[2..9]: fw_*/bw_* encoder weights — provably unused (softmax over a
    // broadcast scalar logit is uniform 1/N regardless of the logit value).
    const float* Wv     = (const float*)d_in[10];
    const float* fu_W1  = (const float*)d_in[11];
    const float* fu_b1  = (const float*)d_in[12];
    const float* fu_W2  = (const float*)d_in[13];
    const float* fu_b2  = (const float*)d_in[14];
    const float* Wo     = (const float*)d_in[15];
    const float* cratio = (const float*)d_in[16];

    float* out = (float*)d_out;
    float* ws  = (float*)d_ws;
    unsigned short* hbf   = (unsigned short*)(ws + OFF_HBF);
    unsigned short* Xbf   = (unsigned short*)(ws + OFF_XBF);
    unsigned short* Wvbf  = (unsigned short*)(ws + OFF_WVBF);
    unsigned short* Mbf   = (unsigned short*)(ws + OFF_MBF);
    unsigned short* W1abf = (unsigned short*)(ws + OFF_W1A);
    float* hbar = ws + OFF_HBAR;
    float* bias = ws + OFF_BIAS;

    // P1: casts + hbar + M-collapse + bias (all independent, atomic-free)
    k_prep<<<752, 256, 0, stream>>>(h, Wv, fu_W1, Wo, fu_W2, fu_b2,
                                    hbf, Wvbf, W1abf, Mbf, hbar, bias);
    // GEMM1: HF = h @ Wv^T (bf16 MFMA), fused in-block cvec + per-head MLP
    // layer1 + GELU -> X   (cvec folded: the old 32-block k_cvec node is gone)
    k_mm<1><<<dim3(32, 16), 256, 0, stream>>>(hbf, Wvbf, Xbf, W1abf, hbar,
                                              fu_W1, fu_b1, nullptr,
                                              nullptr, nullptr);
    // GEMM2: out = X @ M^T + bias (fu_W2/Wo pre-collapsed into M); fused tail
    k_mm<0><<<dim3(32, 16), 256, 0, stream>>>(Xbf, Mbf, out, nullptr, nullptr,
                                              nullptr, nullptr, bias,
                                              prev, cratio);
}

// Round 6
// 176.548 us; speedup vs baseline: 1.0500x; 1.0500x over previous
//
#include <hip/hip_runtime.h>
#include <hip/hip_bf16.h>

// Problem constants: D=1024, H=16, HD=64, B=2, N=1024, rows = B*N = 2048.

typedef __attribute__((ext_vector_type(8))) short bf16x8;
typedef __attribute__((ext_vector_type(4))) float f32x4;

// ws layout (float offsets).
#define OFF_HBF  0                 // h cast to bf16        [2048][1024] us
#define OFF_XBF  1048576           // X (gelu out) bf16     [2048][1024] us
#define OFF_WVBF 2097152           // Wv bf16               [1024][1024] us
#define OFF_MBF  2621440           // M = Wo(x)fu_W2 bf16   [1024][1024] us
#define OFF_W1A  3145728           // fu_W1[:,:,0:64] bf16  [16][64][64] us
#define OFF_HBAR 3178496           // mean of h over n [2][1024]   (memset w/ bias)
#define OFF_BIAS 3180544           // bias_vec = Wo @ fu_b2 [1024] (memset w/ hbar)
#define OFF_C    3181568           // c vec per (b,head,e) [2][1024]

__device__ __forceinline__ unsigned short f2bf(float f) {
    unsigned int u = __float_as_uint(f);
    u += 0x7fffu + ((u >> 16) & 1u);   // round-to-nearest-even
    return (unsigned short)(u >> 16);
}

__device__ __forceinline__ void async_load16(const void* g, void* l) {
    __builtin_amdgcn_global_load_lds(
        (const __attribute__((address_space(1))) unsigned int*)g,
        (__attribute__((address_space(3))) unsigned int*)l, 16, 0, 0);
}

// ---------------------------------------------------------------------------
// PREP1 (grid 1216): blk<128 : cast h->bf16 + hbar atomic partials (16 rows/blk)
//                    128..1151: cast Wv->bf16 (1024 elems/blk, float4)
//                    1152..1215: cast fu_W1[:,:,0:64] -> W1a bf16
// ---------------------------------------------------------------------------
__global__ __launch_bounds__(256) void k_prep1(const float* __restrict__ h,
                                               const float* __restrict__ Wv,
                                               const float* __restrict__ fu_W1,
                                               unsigned short* __restrict__ hbf,
                                               unsigned short* __restrict__ Wvbf,
                                               unsigned short* __restrict__ W1abf,
                                               float* __restrict__ hbar) {
    int blk = blockIdx.x, tid = threadIdx.x;
    if (blk < 128) {
        int b = blk >> 6, chunk = blk & 63;
        int n0 = chunk * 16, d0 = tid * 4;
        const float* hb = h + (size_t)b * 1048576 + d0;
        unsigned short* ob = hbf + (size_t)b * 1048576 + d0;
        float4 sum = make_float4(0.f, 0.f, 0.f, 0.f);
#pragma unroll
        for (int i = 0; i < 16; ++i) {
            float4 v = *(const float4*)(hb + (size_t)(n0 + i) * 1024);
            sum.x += v.x; sum.y += v.y; sum.z += v.z; sum.w += v.w;
            *(ushort4*)(ob + (size_t)(n0 + i) * 1024) =
                make_ushort4(f2bf(v.x), f2bf(v.y), f2bf(v.z), f2bf(v.w));
        }
        float* hp = hbar + b * 1024 + d0;
        atomicAdd(hp + 0, sum.x * (1.f / 1024.f));
        atomicAdd(hp + 1, sum.y * (1.f / 1024.f));
        atomicAdd(hp + 2, sum.z * (1.f / 1024.f));
        atomicAdd(hp + 3, sum.w * (1.f / 1024.f));
    } else if (blk < 1152) {
        int i0 = (blk - 128) * 1024 + tid * 4;
        float4 v = *(const float4*)(Wv + i0);
        *(ushort4*)(Wvbf + i0) =
            make_ushort4(f2bf(v.x), f2bf(v.y), f2bf(v.z), f2bf(v.w));
    } else {
        int blk2 = blk - 1152;                 // 0..63
        int hh = blk2 >> 2, q = blk2 & 3;
        int e = q * 16 + (tid >> 4);
        int k4 = (tid & 15) * 4;
        float4 v = *(const float4*)(fu_W1 + (size_t)(hh * 64 + e) * 192 + k4);
        *(ushort4*)(W1abf + hh * 4096 + e * 64 + k4) =
            make_ushort4(f2bf(v.x), f2bf(v.y), f2bf(v.z), f2bf(v.w));
    }
}

// ---------------------------------------------------------------------------
// PREP2 (grid 288): blk<256 : M[e',h64+e] = sum_f Wo[e',h64+f]*fu_W2[h,f,e]
//                   (LDS-staged, coalesced; fused bias partial via atomics)
//                   256..287: cvec (per b,head): mf = Wv.hbar, c = b1+(W1b+W1c)mf
// ---------------------------------------------------------------------------
__global__ __launch_bounds__(256) void k_prep2(const float* __restrict__ Wo,
                                               const float* __restrict__ fu_W2,
                                               const float* __restrict__ fu_b2,
                                               const float* __restrict__ Wv,
                                               const float* __restrict__ fu_W1,
                                               const float* __restrict__ fu_b1,
                                               const float* __restrict__ hbar,
                                               unsigned short* __restrict__ Mbf,
                                               float* __restrict__ bias,
                                               float* __restrict__ cvec) {
    __shared__ float smem[8384];   // W2s[64][65] + Wos[64][65] + b2s[64]
    int blk = blockIdx.x, tid = threadIdx.x;
    if (blk < 256) {
        float* W2s = smem;               // [f][e] stride 65
        float* Wos = smem + 4160;        // [r][f] stride 65
        float* b2s = smem + 8320;
        int rc = blk >> 4, hh = blk & 15;
        int r0 = rc * 64;
#pragma unroll
        for (int i = 0; i < 16; ++i) {
            int idx = tid + i * 256;
            int f = idx >> 6, e = idx & 63;
            W2s[f * 65 + e] = fu_W2[hh * 4096 + idx];
            Wos[f * 65 + e] = Wo[(size_t)(r0 + f) * 1024 + hh * 64 + e];
        }
        if (tid < 64) b2s[tid] = fu_b2[hh * 64 + tid];
        __syncthreads();
        // each thread: 2 rows x 8 cols
        int ty = tid >> 3, tx = tid & 7;
        int r1 = 2 * ty, r2 = 2 * ty + 1, e0 = tx * 8;
        float acc0[8], acc1[8];
#pragma unroll
        for (int j = 0; j < 8; ++j) { acc0[j] = 0.f; acc1[j] = 0.f; }
        for (int f = 0; f < 64; ++f) {
            float a0 = Wos[r1 * 65 + f], a1 = Wos[r2 * 65 + f];
            const float* w2r = &W2s[f * 65 + e0];
#pragma unroll
            for (int j = 0; j < 8; ++j) {
                float b = w2r[j];
                acc0[j] += a0 * b;
                acc1[j] += a1 * b;
            }
        }
        unsigned short* m1 = Mbf + (size_t)(r0 + r1) * 1024 + hh * 64 + e0;
        unsigned short* m2 = Mbf + (size_t)(r0 + r2) * 1024 + hh * 64 + e0;
        *(ushort4*)(m1) = make_ushort4(f2bf(acc0[0]), f2bf(acc0[1]), f2bf(acc0[2]), f2bf(acc0[3]));
        *(ushort4*)(m1 + 4) = make_ushort4(f2bf(acc0[4]), f2bf(acc0[5]), f2bf(acc0[6]), f2bf(acc0[7]));
        *(ushort4*)(m2) = make_ushort4(f2bf(acc1[0]), f2bf(acc1[1]), f2bf(acc1[2]), f2bf(acc1[3]));
        *(ushort4*)(m2 + 4) = make_ushort4(f2bf(acc1[4]), f2bf(acc1[5]), f2bf(acc1[6]), f2bf(acc1[7]));
        // fused bias partial: bias[r0+r] += sum_f Wos[r][f]*b2s[f]
        if (tid < 64) {
            float p = 0.f;
#pragma unroll 8
            for (int f = 0; f < 64; ++f) p += Wos[tid * 65 + f] * b2s[f];
            atomicAdd(&bias[r0 + tid], p);
        }
    } else {
        float* psum = smem;              // [64][4]
        float* mf = smem + 256;          // [64]
        int blk2 = blk - 256;
        int b = blk2 >> 4, hh = blk2 & 15;
        int e = tid >> 2, sl = tid & 3;
        const float* wrow = Wv + (size_t)(hh * 64 + e) * 1024;
        const float* hb = hbar + b * 1024;
        float s = 0.f;
        int k0 = sl * 256;
        for (int k = k0; k < k0 + 256; ++k) s += wrow[k] * hb[k];
        psum[e * 4 + sl] = s;
        __syncthreads();
        if (tid < 64)
            mf[tid] = psum[tid * 4] + psum[tid * 4 + 1] + psum[tid * 4 + 2] + psum[tid * 4 + 3];
        __syncthreads();
        if (tid < 64) {
            const float* w1 = fu_W1 + (size_t)(hh * 64 + tid) * 192;
            float acc = fu_b1[hh * 64 + tid];
            for (int k = 0; k < 64; ++k) acc += (w1[64 + k] + w1[128 + k]) * mf[k];
            cvec[b * 1024 + hh * 64 + tid] = acc;
        }
    }
}

// ---------------------------------------------------------------------------
// GEMM: C = A[2048xK=1024] @ W[1024x1024]^T, bf16 MFMA.
// BM=32, BN=64, BK=64, 256 thr (4 waves, each 16x32 = 1x2 16x16 tiles).
// grid (64,16) = 1024 blocks = 4 blocks/CU.
// DOUBLE-BUFFERED LDS, ONE barrier/iter: sync publishes buf `cur` (whose
// loads were issued a full compute-phase earlier -> near-zero vmcnt drain),
// then issue buf `next` loads, then compute on `cur`.  This removes the
// exposed full-latency drain of the 2-barrier structure (R1-R5).
// LDS: As[2][32][64]bf16 (2x4K) + Bs[2][64][64]bf16 (2x8K) = 24 KB, XOR-swizzle
//   byte(r,c) = r*128 + (((c>>3)^(r&7))<<4) + (c&7)*2  -> <=2-way conflicts.
// MODE 1: epilogue = per-head 64x64 MLP (HF->LDS A-layout, W1a as B) + c +
//         exact GELU -> X bf16 (coalesced via LDS).
// MODE 0: + bias -> fp32 out via LDS float4 stores; fused tail in block (0,0).
// ---------------------------------------------------------------------------
template <int MODE>
__global__ __launch_bounds__(256) void k_mm(const unsigned short* __restrict__ A,
                                            const unsigned short* __restrict__ Bw,
                                            void* __restrict__ CoutV,
                                            const unsigned short* __restrict__ W1a,
                                            const float* __restrict__ cvec,
                                            const float* __restrict__ bias,
                                            const int* __restrict__ prev_idx,
                                            const float* __restrict__ chain_ratio) {
    __shared__ __align__(16) char smem[24576];
    // buffers: As0 @0, As1 @4096, Bs0 @8192, Bs1 @16384
    const int tid = threadIdx.x;
    const int w = tid >> 6, lane = tid & 63;
    const int rowBase = blockIdx.x * 32, colBase = blockIdx.y * 64;
    const int wmh = (w >> 1) * 16, wnh = (w & 1) * 32;
    const int lr = lane >> 3;                 // staging row within 8-row chunk
    const int ssrc = ((lane & 7) ^ lr) * 8;   // swizzled source k offset (elems)
    const int m_lane = lane & 15, quad = lane >> 4;

    if (MODE == 0 && blockIdx.x == 0 && blockIdx.y == 0) {
        // fused tail: targets + strength (closed-form: uniform softmax over a
        // broadcast scalar logit -> target 511 / chained prev_idx).
        float* out = (float*)CoutV;
        float cr = chain_ratio[0];
        float thr = floorf(1024.0f / (1.0f + expf(-cr)));
        float strength = 1.0f - logf(1.0f / 1024.0f + 1e-8f);
        for (int i = tid; i < 2048; i += 256) {
            int n = i & 1023;
            float fwd = 511.0f;
            if ((float)n >= thr) {
                int p = prev_idx[i];
                p = p < 0 ? 0 : (p > 1023 ? 1023 : p);
                fwd = (float)p;
            }
            out[2097152 + i] = fwd;
            out[2097152 + 2048 + i] = 511.0f;
            out[2097152 + 4096 + i] = strength;
        }
    }

    const unsigned short* Ag = A + (size_t)(rowBase + w * 8 + lr) * 1024 + ssrc;
    const unsigned short* Bg0 = Bw + (size_t)(colBase + w * 8 + lr) * 1024 + ssrc;
    const unsigned short* Bg1 = Bg0 + (size_t)32 * 1024;
    const int woff = w * 1024;                 // wave-uniform LDS staging offset

    f32x4 acc[2];
    acc[0] = (f32x4){0.f, 0.f, 0.f, 0.f};
    acc[1] = (f32x4){0.f, 0.f, 0.f, 0.f};

    // prologue: issue buf0 loads
    async_load16(Ag, smem + woff);
    async_load16(Bg0, smem + 8192 + woff);
    async_load16(Bg1, smem + 8192 + woff + 4096);

    for (int k0 = 0; k0 < 1024; k0 += 64) {
        const int cur = (k0 >> 6) & 1;
        char* Asc = smem + cur * 4096;
        char* Bsc = smem + 8192 + cur * 8192;
        __syncthreads();     // publishes buf cur (its loads issued 1 iter ago)
        if (k0 + 64 < 1024) {
            char* Asn = smem + (cur ^ 1) * 4096;
            char* Bsn = smem + 8192 + (cur ^ 1) * 8192;
            async_load16(Ag + k0 + 64, Asn + woff);
            async_load16(Bg0 + k0 + 64, Bsn + woff);
            async_load16(Bg1 + k0 + 64, Bsn + woff + 4096);
        }
#pragma unroll
        for (int kh = 0; kh < 2; ++kh) {
            const int seg = kh * 4 + quad;
            const int m = wmh + m_lane;
            bf16x8 af = *(const bf16x8*)(Asc + m * 128 + ((seg ^ (m & 7)) << 4));
#pragma unroll
            for (int nt = 0; nt < 2; ++nt) {
                int n = wnh + nt * 16 + m_lane;
                bf16x8 bfr = *(const bf16x8*)(Bsc + n * 128 + ((seg ^ (n & 7)) << 4));
                acc[nt] = __builtin_amdgcn_mfma_f32_16x16x32_bf16(af, bfr, acc[nt], 0, 0, 0);
            }
        }
    }

    char* As = smem;            // epilogue uses buffer-0 regions
    char* Bs = smem + 8192;
    if (MODE == 0) {
        float* out = (float*)CoutV;
        float* Os = (float*)smem;              // [32][68] fp32, 8704 B
        __syncthreads();                       // main-loop LDS reads done
#pragma unroll
        for (int nt = 0; nt < 2; ++nt) {
            int c = wnh + nt * 16 + m_lane;
            float bj = bias[colBase + c];
#pragma unroll
            for (int r4 = 0; r4 < 4; ++r4) {
                int r = wmh + quad * 4 + r4;
                Os[r * 68 + c] = acc[nt][r4] + bj;
            }
        }
        __syncthreads();
#pragma unroll
        for (int j = 0; j < 2; ++j) {
            int sidx = tid + j * 256;
            int r = sidx >> 4, sc = sidx & 15;
            float4 v = *(const float4*)&Os[r * 68 + sc * 4];
            *(float4*)&out[(size_t)(rowBase + r) * 1024 + colBase + sc * 4] = v;
        }
    } else {
        unsigned short* Xbf = (unsigned short*)CoutV;
        const int hh = blockIdx.y;             // head for this 64-col block
        __syncthreads();                       // main-loop LDS reads done
        // stage W1a head block [64 e_out][64 e_in] into Bs0 (swizzled, async)
        const unsigned short* Wg = W1a + hh * 4096 + (w * 8 + lr) * 64 + ssrc;
        async_load16(Wg, Bs + woff);
        async_load16(Wg + 32 * 64, Bs + woff + 4096);
        // write HF (bf16 of acc) into As0 in A-fragment (swizzled) layout
#pragma unroll
        for (int nt = 0; nt < 2; ++nt) {
            int c = wnh + nt * 16 + m_lane;
#pragma unroll
            for (int r4 = 0; r4 < 4; ++r4) {
                int r = wmh + quad * 4 + r4;
                *(unsigned short*)(As + r * 128 + (((c >> 3) ^ (r & 7)) << 4) +
                                   (c & 7) * 2) = f2bf(acc[nt][r4]);
            }
        }
        __syncthreads();                       // drains vmcnt -> W1a staged
        f32x4 acc2[2];
        acc2[0] = (f32x4){0.f, 0.f, 0.f, 0.f};
        acc2[1] = (f32x4){0.f, 0.f, 0.f, 0.f};
#pragma unroll
        for (int kh = 0; kh < 2; ++kh) {
            const int seg = kh * 4 + quad;
            const int m = wmh + m_lane;
            bf16x8 af = *(const bf16x8*)(As + m * 128 + ((seg ^ (m & 7)) << 4));
#pragma unroll
            for (int nt = 0; nt < 2; ++nt) {
                int n = wnh + nt * 16 + m_lane;
                bf16x8 bfr = *(const bf16x8*)(Bs + n * 128 + ((seg ^ (n & 7)) << 4));
                acc2[nt] = __builtin_amdgcn_mfma_f32_16x16x32_bf16(af, bfr, acc2[nt], 0, 0, 0);
            }
        }
        __syncthreads();                       // HF reads done; As reusable
        const int b = rowBase >> 10;
#pragma unroll
        for (int nt = 0; nt < 2; ++nt) {
            int c = wnh + nt * 16 + m_lane;
            float cadd = cvec[b * 1024 + hh * 64 + c];
#pragma unroll
            for (int r4 = 0; r4 < 4; ++r4) {
                int r = wmh + quad * 4 + r4;
                float t = acc2[nt][r4] + cadd;
                t = 0.5f * t * (1.0f + erff(t * 0.70710678118654752f));
                *(unsigned short*)(As + r * 128 + c * 2) = f2bf(t);  // plain layout
            }
        }
        __syncthreads();
        // coalesced X store: 32 rows x 8 16B-segs = 256, 1 per thread
        int r = tid >> 3, s = tid & 7;
        float4 v = *(const float4*)(As + r * 128 + s * 16);
        *(float4*)((char*)Xbf + ((size_t)(rowBase + r) * 1024 + colBase + s * 8) * 2) = v;
    }
}

// ---------------------------------------------------------------------------
extern "C" void kernel_launch(void* const* d_in, const int* in_sizes, int n_in,
                              void* d_out, int out_size, void* d_ws, size_t ws_size,
                              hipStream_t stream) {
    const float* h      = (const float*)d_in[0];
    const int*   prev   = (const int*)d_in[1];
    // d_in[2..9]: fw_*/bw_* encoder weights — provably unused (softmax over a
    // broadcast scalar logit is uniform 1/N regardless of the logit value).
    const float* Wv     = (const float*)d_in[10];
    const float* fu_W1  = (const float*)d_in[11];
    const float* fu_b1  = (const float*)d_in[12];
    const float* fu_W2  = (const float*)d_in[13];
    const float* fu_b2  = (const float*)d_in[14];
    const float* Wo     = (const float*)d_in[15];
    const float* cratio = (const float*)d_in[16];

    float* out = (float*)d_out;
    float* ws  = (float*)d_ws;
    unsigned short* hbf   = (unsigned short*)(ws + OFF_HBF);
    unsigned short* Xbf   = (unsigned short*)(ws + OFF_XBF);
    unsigned short* Wvbf  = (unsigned short*)(ws + OFF_WVBF);
    unsigned short* Mbf   = (unsigned short*)(ws + OFF_MBF);
    unsigned short* W1abf = (unsigned short*)(ws + OFF_W1A);
    float* hbar = ws + OFF_HBAR;
    float* bias = ws + OFF_BIAS;
    float* cv   = ws + OFF_C;

    // zero hbar (2048) + bias (1024) — contiguous, one 12 KB memset
    hipMemsetAsync(hbar, 0, 3072 * sizeof(float), stream);
    k_prep1<<<1216, 256, 0, stream>>>(h, Wv, fu_W1, hbf, Wvbf, W1abf, hbar);
    k_prep2<<<288, 256, 0, stream>>>(Wo, fu_W2, fu_b2, Wv, fu_W1, fu_b1, hbar,
                                     Mbf, bias, cv);
    // GEMM1: HF = h @ Wv^T (bf16 MFMA), fused per-head MLP layer1 + GELU -> X
    k_mm<1><<<dim3(64, 16), 256, 0, stream>>>(hbf, Wvbf, Xbf, W1abf, cv,
                                              nullptr, nullptr, nullptr);
    // GEMM2: out = X @ M^T + bias (fu_W2/Wo pre-collapsed into M); fused tail
    k_mm<0><<<dim3(64, 16), 256, 0, stream>>>(Xbf, Mbf, out, nullptr, nullptr,
                                              bias, prev, cratio);
}